// Round 1
// baseline (99249.768 us; speedup 1.0000x reference)
//
#include <hip/hip_runtime.h>
#include <math.h>

constexpr int H   = 512;
constexpr int B   = 512;
constexpr int T   = 256;
constexpr int F   = 8;
constexpr int HOR = 24;

__device__ __forceinline__ float sigm(float x) { return 1.0f / (1.0f + expf(-x)); }

// Fused LSTM cell step: z = xin@Wih^T + hprev@Whh^T + (bih+bhh); gates; c,h update.
// Layouts: all weights [4H][kin] row-major (gate-major: rows 0..H-1 = i, H..2H-1 = f,
// 2H..3H-1 = g, 3H..4H-1 = o). h/c buffers [B][H] row-major.
// Small-kin path (kin<=8): xin indexed [b*xs_stride + k].
// Big path (kin==H): xin is an [B][H] activation read via LDS tiles like hprev.
// Block: 256 threads; tx=tid&31 -> jh col in 32-wide tile, ty=tid>>5 -> pair of batch rows.
// Grid: 512 blocks = (bid&15)->jh tile, (bid>>4)->16-row batch tile. 2 blocks/CU.
__global__ __launch_bounds__(256)
void cell_k(const float* __restrict__ xs, int xs_stride, int kin,
            const float* __restrict__ Wih,
            const float* __restrict__ Whh,
            const float* __restrict__ bih, const float* __restrict__ bhh,
            const float* __restrict__ hprev,
            float* __restrict__ cst, float* __restrict__ hout)
{
    __shared__ float Hs[16][32];   // 2 KB: [batch row][k] tile of current big source
    const int tid = threadIdx.x;
    const int tx  = tid & 31;
    const int ty  = tid >> 5;
    const int jh  = ((blockIdx.x & 15) << 5) + tx;
    const int bm0 = (blockIdx.x >> 4) << 4;
    const int bl0 = ty * 2;

    float acc0[4] = {0.f, 0.f, 0.f, 0.f};
    float acc1[4] = {0.f, 0.f, 0.f, 0.f};

    // small input contribution (enc0: kin=8, dec0: kin=1)
    if (kin <= 8) {
        const float* xr0 = xs + (size_t)(bm0 + bl0) * xs_stride;
        const float* xr1 = xr0 + xs_stride;
        for (int k = 0; k < kin; ++k) {
            float x0 = xr0[k], x1 = xr1[k];
            #pragma unroll
            for (int g = 0; g < 4; ++g) {
                float w = Wih[(size_t)(g * H + jh) * kin + k];
                acc0[g] += x0 * w;
                acc1[g] += x1 * w;
            }
        }
    }

    // big-K sources: optionally (xs, Wih) when kin==H, always (hprev, Whh)
    for (int s = (kin == H ? 0 : 1); s < 2; ++s) {
        const float* P = (s == 0) ? xs : hprev;
        const float* W = (s == 0) ? Wih : Whh;
        const float* Wr0 = W + (size_t)jh * H;   // gate-0 row for this jh; gate g at +g*H*H
        for (int k0 = 0; k0 < H; k0 += 32) {
            __syncthreads();
            if (tid < 128) {
                int bb = tid >> 3, kq = tid & 7;
                *(float4*)(&Hs[bb][kq * 4]) =
                    *(const float4*)(&P[(size_t)(bm0 + bb) * H + k0 + kq * 4]);
            }
            __syncthreads();
            #pragma unroll
            for (int kq = 0; kq < 8; ++kq) {
                const int ko = k0 + kq * 4;
                float4 w0 = *(const float4*)(&Wr0[ko]);
                float4 w1 = *(const float4*)(&Wr0[(size_t)1 * H * H + ko]);
                float4 w2 = *(const float4*)(&Wr0[(size_t)2 * H * H + ko]);
                float4 w3 = *(const float4*)(&Wr0[(size_t)3 * H * H + ko]);
                float4 ha = *(const float4*)(&Hs[bl0][kq * 4]);
                float4 hb = *(const float4*)(&Hs[bl0 + 1][kq * 4]);
                acc0[0] += ha.x*w0.x + ha.y*w0.y + ha.z*w0.z + ha.w*w0.w;
                acc0[1] += ha.x*w1.x + ha.y*w1.y + ha.z*w1.z + ha.w*w1.w;
                acc0[2] += ha.x*w2.x + ha.y*w2.y + ha.z*w2.z + ha.w*w2.w;
                acc0[3] += ha.x*w3.x + ha.y*w3.y + ha.z*w3.z + ha.w*w3.w;
                acc1[0] += hb.x*w0.x + hb.y*w0.y + hb.z*w0.z + hb.w*w0.w;
                acc1[1] += hb.x*w1.x + hb.y*w1.y + hb.z*w1.z + hb.w*w1.w;
                acc1[2] += hb.x*w2.x + hb.y*w2.y + hb.z*w2.z + hb.w*w2.w;
                acc1[3] += hb.x*w3.x + hb.y*w3.y + hb.z*w3.z + hb.w*w3.w;
            }
        }
    }

    // gates + state update (each (b,jh) owned by exactly one thread -> c in-place safe)
    float bsum[4];
    #pragma unroll
    for (int g = 0; g < 4; ++g) bsum[g] = bih[g * H + jh] + bhh[g * H + jh];

    #pragma unroll
    for (int bb = 0; bb < 2; ++bb) {
        const float* a = bb ? acc1 : acc0;
        int bg = bm0 + bl0 + bb;
        float iz = a[0] + bsum[0];
        float fz = a[1] + bsum[1];
        float gz = a[2] + bsum[2];
        float oz = a[3] + bsum[3];
        size_t idx = (size_t)bg * H + jh;
        float cold = cst[idx];
        float cn = sigm(fz) * cold + sigm(iz) * tanhf(gz);
        cst[idx] = cn;
        hout[idx] = sigm(oz) * tanhf(cn);
    }
}

// pred[b] = dot(h1[b,:], outW) + outb; also writes d_out[b][tstep].
__global__ __launch_bounds__(256)
void pred_k(const float* __restrict__ h1, const float* __restrict__ outW,
            const float* __restrict__ outb, float* __restrict__ pred,
            float* __restrict__ dout, int tstep)
{
    int wv = threadIdx.x >> 6, lane = threadIdx.x & 63;
    int b = (blockIdx.x << 2) + wv;
    const float* hr = h1 + (size_t)b * H;
    float s = 0.f;
    #pragma unroll
    for (int k = 0; k < H; k += 64) s += hr[k + lane] * outW[k + lane];
    #pragma unroll
    for (int off = 32; off > 0; off >>= 1) s += __shfl_down(s, off);
    if (lane == 0) {
        float p = s + outb[0];
        pred[b] = p;
        dout[(size_t)b * HOR + tstep] = p;
    }
}

// dec_in = x[:, T-1, 0]
__global__ void initpred_k(const float* __restrict__ x, float* __restrict__ pred)
{
    int b = blockIdx.x * 256 + threadIdx.x;
    if (b < B) pred[b] = x[(size_t)b * T * F + (size_t)(T - 1) * F];
}

extern "C" void kernel_launch(void* const* d_in, const int* in_sizes, int n_in,
                              void* d_out, int out_size, void* d_ws, size_t ws_size,
                              hipStream_t stream)
{
    const float* x     = (const float*)d_in[0];
    const float* eWih0 = (const float*)d_in[1];
    const float* eWhh0 = (const float*)d_in[2];
    const float* ebih0 = (const float*)d_in[3];
    const float* ebhh0 = (const float*)d_in[4];
    const float* eWih1 = (const float*)d_in[5];
    const float* eWhh1 = (const float*)d_in[6];
    const float* ebih1 = (const float*)d_in[7];
    const float* ebhh1 = (const float*)d_in[8];
    const float* dWih0 = (const float*)d_in[9];
    const float* dWhh0 = (const float*)d_in[10];
    const float* dbih0 = (const float*)d_in[11];
    const float* dbhh0 = (const float*)d_in[12];
    const float* dWih1 = (const float*)d_in[13];
    const float* dWhh1 = (const float*)d_in[14];
    const float* dbih1 = (const float*)d_in[15];
    const float* dbhh1 = (const float*)d_in[16];
    const float* outW  = (const float*)d_in[17];
    const float* outb  = (const float*)d_in[18];
    float* out = (float*)d_out;

    const size_t BH = (size_t)B * H;
    float* ws   = (float*)d_ws;
    float* h0   = ws;            // 2 ping-pong slots
    float* h1   = ws + 2 * BH;   // 2 ping-pong slots
    float* c0   = ws + 4 * BH;
    float* c1   = ws + 5 * BH;
    float* pred = ws + 6 * BH;   // B floats

    // deterministic init every call (harness does not re-poison between replays)
    hipMemsetAsync(h0, 0, BH * sizeof(float), stream);
    hipMemsetAsync(h1, 0, BH * sizeof(float), stream);
    hipMemsetAsync(c0, 0, BH * sizeof(float), stream);
    hipMemsetAsync(c1, 0, BH * sizeof(float), stream);

    dim3 grid(512), blk(256);

    // encoder: layer0 then layer1 each step (layer1 consumes h0 immediately ->
    // no hs0 materialization)
    for (int t = 0; t < T; ++t) {
        int rd = t & 1, wr = rd ^ 1;
        cell_k<<<grid, blk, 0, stream>>>(x + (size_t)t * F, T * F, F,
                                         eWih0, eWhh0, ebih0, ebhh0,
                                         h0 + rd * BH, c0, h0 + wr * BH);
        cell_k<<<grid, blk, 0, stream>>>(h0 + wr * BH, H, H,
                                         eWih1, eWhh1, ebih1, ebhh1,
                                         h1 + rd * BH, c1, h1 + wr * BH);
    }
    // after t=255: final h0,h1 live in slot 0; c0,c1 in place. Decoder reuses them.

    initpred_k<<<dim3(2), blk, 0, stream>>>(x, pred);

    for (int td = 0; td < HOR; ++td) {
        int rd = td & 1, wr = rd ^ 1;
        cell_k<<<grid, blk, 0, stream>>>(pred, 1, 1,
                                         dWih0, dWhh0, dbih0, dbhh0,
                                         h0 + rd * BH, c0, h0 + wr * BH);
        cell_k<<<grid, blk, 0, stream>>>(h0 + wr * BH, H, H,
                                         dWih1, dWhh1, dbih1, dbhh1,
                                         h1 + rd * BH, c1, h1 + wr * BH);
        pred_k<<<dim3(128), blk, 0, stream>>>(h1 + wr * BH, outW, outb, pred, out, td);
    }
}

// Round 2
// 8711.965 us; speedup vs baseline: 11.3924x; 11.3924x over previous
//
#include <hip/hip_runtime.h>
#include <math.h>

constexpr int H   = 512;
constexpr int B   = 512;
constexpr int T   = 256;
constexpr int F   = 8;
constexpr int HOR = 24;

typedef _Float16 f16;
typedef _Float16 f16x8 __attribute__((ext_vector_type(8)));
typedef float    f32x4 __attribute__((ext_vector_type(4)));

__device__ __forceinline__ float sigm(float x) { return 1.0f / (1.0f + expf(-x)); }

// ---------------------------------------------------------------------------
// Weight convert: fp32 [4H][H] gate-major rows (row = g*H + jh) -> fp16
// [2048][512] permuted rows n' = jh*4 + g (so a 64-col n'-tile = 16 jh x 4 gates).
// grid: (512, 6). Each thread converts 8 contiguous k of one n' row.
__global__ __launch_bounds__(256)
void wconv_k(const float* __restrict__ s0, f16* __restrict__ d0,
             const float* __restrict__ s1, f16* __restrict__ d1,
             const float* __restrict__ s2, f16* __restrict__ d2,
             const float* __restrict__ s3, f16* __restrict__ d3,
             const float* __restrict__ s4, f16* __restrict__ d4,
             const float* __restrict__ s5, f16* __restrict__ d5)
{
    const float* src; f16* dst;
    switch (blockIdx.y) {
        case 0:  src = s0; dst = d0; break;
        case 1:  src = s1; dst = d1; break;
        case 2:  src = s2; dst = d2; break;
        case 3:  src = s3; dst = d3; break;
        case 4:  src = s4; dst = d4; break;
        default: src = s5; dst = d5; break;
    }
    int idx = (blockIdx.x * 256 + threadIdx.x) * 8;   // half index into dst
    int np  = idx >> 9;                               // n' row
    int k   = idx & 511;
    int jh  = np >> 2, g = np & 3;
    const float* sp = src + (size_t)(g * H + jh) * H + k;
    f16 tmp[8];
    #pragma unroll
    for (int j = 0; j < 8; ++j) tmp[j] = (f16)sp[j];
    *(f16x8*)(dst + idx) = *(const f16x8*)tmp;
}

// ---------------------------------------------------------------------------
// Fused LSTM cell: z = A @ W'^T (fp16 MFMA, fp32 acc) + bias + x-path (fp32),
// gates, c/h update. A rows: k<512 from A0, k>=512 from A1 (both [B][512] f16).
// W' rows permuted n' = jh*4+g, [2048][512] f16; k<512 from W0, else W1.
// xmode: 0 none; 1 enc0 (xptr strided fp32, xw = Wih0 [2048][8] fp32);
//        2 dec0 (xptr = pred[B], xw = dWih0 [2048][1] fp32).
// Block: 64 b-rows x 16 jh (64 n'). grid 256 = (b-tile 8) x (n-tile 32).
__global__ __launch_bounds__(256)
void cell16_k(const f16* __restrict__ A0, const f16* __restrict__ A1,
              const f16* __restrict__ W0, const f16* __restrict__ W1,
              int K,
              const float* __restrict__ bih, const float* __restrict__ bhh,
              int xmode, const float* __restrict__ xptr, int xstride,
              const float* __restrict__ xw,
              float* __restrict__ cst, f16* __restrict__ hout)
{
    __shared__ float zs_f[64 * 68];                 // 17408 B; reused: As|Ws then zs
    f16* As = (f16*)zs_f;                           // [64][40] halfs = 5120 B
    f16* Ws = (f16*)zs_f + 64 * 40;                 // [64][40] halfs = 5120 B

    const int tid  = threadIdx.x;
    const int lane = tid & 63;
    const int wv   = tid >> 6;          // wave 0..3
    const int wm   = wv & 1;            // wave m-half
    const int wn   = wv >> 1;           // wave n-half
    const int r    = lane & 15;
    const int g4   = lane >> 4;
    const int bt   = blockIdx.x >> 5;   // 0..7
    const int nt   = blockIdx.x & 31;   // 0..31
    const int b0   = bt * 64;
    const int n0   = nt * 64;           // n' base
    const int jh0  = nt * 16;

    const int srow = tid >> 2;          // staging row 0..63
    const int sch  = tid & 3;           // staging 8-half chunk

    f32x4 acc[2][2] = {};

    const int nkt = K >> 5;
    for (int kt = 0; kt < nkt; ++kt) {
        const f16* Ap = (kt < 16) ? A0 : A1;
        const f16* Wp = (kt < 16) ? W0 : W1;
        const int  ko = (kt < 16) ? kt * 32 : kt * 32 - 512;

        f16x8 av = *(const f16x8*)(Ap + (size_t)(b0 + srow) * H + ko + sch * 8);
        f16x8 wv8 = *(const f16x8*)(Wp + (size_t)(n0 + srow) * H + ko + sch * 8);

        __syncthreads();   // previous iteration's frag reads done
        *(f16x8*)(As + srow * 40 + sch * 8) = av;
        *(f16x8*)(Ws + srow * 40 + sch * 8) = wv8;
        __syncthreads();

        f16x8 af0 = *(const f16x8*)(As + (wm * 32 + r)      * 40 + g4 * 8);
        f16x8 af1 = *(const f16x8*)(As + (wm * 32 + 16 + r) * 40 + g4 * 8);
        f16x8 bf0 = *(const f16x8*)(Ws + (wn * 32 + r)      * 40 + g4 * 8);
        f16x8 bf1 = *(const f16x8*)(Ws + (wn * 32 + 16 + r) * 40 + g4 * 8);

        acc[0][0] = __builtin_amdgcn_mfma_f32_16x16x32_f16(af0, bf0, acc[0][0], 0, 0, 0);
        acc[0][1] = __builtin_amdgcn_mfma_f32_16x16x32_f16(af0, bf1, acc[0][1], 0, 0, 0);
        acc[1][0] = __builtin_amdgcn_mfma_f32_16x16x32_f16(af1, bf0, acc[1][0], 0, 0, 0);
        acc[1][1] = __builtin_amdgcn_mfma_f32_16x16x32_f16(af1, bf1, acc[1][1], 0, 0, 0);
    }

    __syncthreads();   // all frag reads done before zs overwrites As/Ws
    #pragma unroll
    for (int fm = 0; fm < 2; ++fm)
        #pragma unroll
        for (int fn = 0; fn < 2; ++fn)
            #pragma unroll
            for (int j = 0; j < 4; ++j)
                zs_f[(wm * 32 + fm * 16 + g4 * 4 + j) * 68 +
                     (wn * 32 + fn * 16 + r)] = acc[fm][fn][j];
    __syncthreads();

    // epilogue: thread -> (4 b-rows, 1 jh); gates are the 4 consecutive n'.
    const int jl = tid & 15;
    const int bq = tid >> 4;
    const int jh = jh0 + jl;

    float bsum[4];
    #pragma unroll
    for (int g = 0; g < 4; ++g) bsum[g] = bih[g * H + jh] + bhh[g * H + jh];

    #pragma unroll
    for (int bb = 0; bb < 4; ++bb) {
        const int bl = bq * 4 + bb;
        const int b  = b0 + bl;
        float4 z = *(const float4*)(zs_f + bl * 68 + jl * 4);
        float zi = z.x + bsum[0];
        float zf = z.y + bsum[1];
        float zg = z.z + bsum[2];
        float zo = z.w + bsum[3];
        if (xmode == 1) {
            const float* xr = xptr + (size_t)b * xstride;
            #pragma unroll
            for (int k = 0; k < F; ++k) {
                float xv = xr[k];
                zi += xv * xw[(0 * H + jh) * F + k];
                zf += xv * xw[(1 * H + jh) * F + k];
                zg += xv * xw[(2 * H + jh) * F + k];
                zo += xv * xw[(3 * H + jh) * F + k];
            }
        } else if (xmode == 2) {
            float xv = xptr[b];
            zi += xv * xw[0 * H + jh];
            zf += xv * xw[1 * H + jh];
            zg += xv * xw[2 * H + jh];
            zo += xv * xw[3 * H + jh];
        }
        size_t idx = (size_t)b * H + jh;
        float cold = cst[idx];
        float cn = sigm(zf) * cold + sigm(zi) * tanhf(zg);
        cst[idx] = cn;
        hout[idx] = (f16)(sigm(zo) * tanhf(cn));
    }
}

// ---------------------------------------------------------------------------
__global__ __launch_bounds__(256)
void pred16_k(const f16* __restrict__ h1, const float* __restrict__ outW,
              const float* __restrict__ outb, float* __restrict__ pred,
              float* __restrict__ dout, int tstep)
{
    int wv = threadIdx.x >> 6, lane = threadIdx.x & 63;
    int b = blockIdx.x * 4 + wv;
    const f16* hr = h1 + (size_t)b * H;
    float s = 0.f;
    #pragma unroll
    for (int k = 0; k < H; k += 64) s += (float)hr[k + lane] * outW[k + lane];
    #pragma unroll
    for (int off = 32; off > 0; off >>= 1) s += __shfl_down(s, off);
    if (lane == 0) {
        float p = s + outb[0];
        pred[b] = p;
        dout[(size_t)b * HOR + tstep] = p;
    }
}

__global__ void initpred_k(const float* __restrict__ x, float* __restrict__ pred)
{
    int b = blockIdx.x * 256 + threadIdx.x;
    if (b < B) pred[b] = x[(size_t)b * T * F + (size_t)(T - 1) * F];
}

// ---------------------------------------------------------------------------
extern "C" void kernel_launch(void* const* d_in, const int* in_sizes, int n_in,
                              void* d_out, int out_size, void* d_ws, size_t ws_size,
                              hipStream_t stream)
{
    const float* x     = (const float*)d_in[0];
    const float* eWih0 = (const float*)d_in[1];
    const float* eWhh0 = (const float*)d_in[2];
    const float* ebih0 = (const float*)d_in[3];
    const float* ebhh0 = (const float*)d_in[4];
    const float* eWih1 = (const float*)d_in[5];
    const float* eWhh1 = (const float*)d_in[6];
    const float* ebih1 = (const float*)d_in[7];
    const float* ebhh1 = (const float*)d_in[8];
    const float* dWih0 = (const float*)d_in[9];
    const float* dWhh0 = (const float*)d_in[10];
    const float* dbih0 = (const float*)d_in[11];
    const float* dbhh0 = (const float*)d_in[12];
    const float* dWih1 = (const float*)d_in[13];
    const float* dWhh1 = (const float*)d_in[14];
    const float* dbih1 = (const float*)d_in[15];
    const float* dbhh1 = (const float*)d_in[16];
    const float* outW  = (const float*)d_in[17];
    const float* outb  = (const float*)d_in[18];
    float* out = (float*)d_out;

    const size_t WSZ = (size_t)4 * H * H;     // halfs per weight (2048*512)
    const size_t BH  = (size_t)B * H;

    char* wsb = (char*)d_ws;
    size_t off = 0;
    f16* wh[6];
    for (int i = 0; i < 6; ++i) { wh[i] = (f16*)(wsb + off); off += WSZ * sizeof(f16); }
    f16* h0p[2]; f16* h1p[2];
    h0p[0] = (f16*)(wsb + off); off += BH * sizeof(f16);
    h0p[1] = (f16*)(wsb + off); off += BH * sizeof(f16);
    h1p[0] = (f16*)(wsb + off); off += BH * sizeof(f16);
    h1p[1] = (f16*)(wsb + off); off += BH * sizeof(f16);
    float* c0   = (float*)(wsb + off); off += BH * sizeof(float);
    float* c1   = (float*)(wsb + off); off += BH * sizeof(float);
    float* pred = (float*)(wsb + off); off += B * sizeof(float);

    // fp16 weight conversion (permuted layout), every call (deterministic)
    wconv_k<<<dim3(512, 6), 256, 0, stream>>>(eWhh0, wh[0], eWih1, wh[1], eWhh1, wh[2],
                                              dWhh0, wh[3], dWih1, wh[4], dWhh1, wh[5]);

    hipMemsetAsync(h0p[0], 0, BH * sizeof(f16), stream);
    hipMemsetAsync(h1p[0], 0, BH * sizeof(f16), stream);
    hipMemsetAsync(c0, 0, BH * sizeof(float), stream);
    hipMemsetAsync(c1, 0, BH * sizeof(float), stream);

    dim3 grid(256), blk(256);

    for (int t = 0; t < T; ++t) {
        int rd = t & 1, wr = rd ^ 1;
        // enc layer0: K=512 recurrent MFMA + fp32 x-path (K=8) in epilogue
        cell16_k<<<grid, blk, 0, stream>>>(h0p[rd], h0p[rd], wh[0], wh[0], 512,
                                           ebih0, ebhh0,
                                           1, x + (size_t)t * F, T * F, eWih0,
                                           c0, h0p[wr]);
        // enc layer1: K=1024 = [h0_new | h1_prev], W = [Wih1 | Whh1]
        cell16_k<<<grid, blk, 0, stream>>>(h0p[wr], h1p[rd], wh[1], wh[2], 1024,
                                           ebih1, ebhh1,
                                           0, nullptr, 0, nullptr,
                                           c1, h1p[wr]);
    }

    initpred_k<<<dim3(2), blk, 0, stream>>>(x, pred);

    for (int td = 0; td < HOR; ++td) {
        int rd = td & 1, wr = rd ^ 1;
        // dec layer0: K=512 recurrent MFMA + fp32 pred-path (K=1) in epilogue
        cell16_k<<<grid, blk, 0, stream>>>(h0p[rd], h0p[rd], wh[3], wh[3], 512,
                                           dbih0, dbhh0,
                                           2, pred, 0, dWih0,
                                           c0, h0p[wr]);
        // dec layer1: K=1024 = [h0_new | h1_prev]
        cell16_k<<<grid, blk, 0, stream>>>(h0p[wr], h1p[rd], wh[4], wh[5], 1024,
                                           dbih1, dbhh1,
                                           0, nullptr, 0, nullptr,
                                           c1, h1p[wr]);
        pred16_k<<<dim3(128), blk, 0, stream>>>(h1p[wr], outW, outb, pred, out, td);
    }
}

// Round 3
// 4154.515 us; speedup vs baseline: 23.8896x; 2.0970x over previous
//
#include <hip/hip_runtime.h>
#include <math.h>

constexpr int H   = 512;
constexpr int B   = 512;
constexpr int T   = 256;
constexpr int F   = 8;
constexpr int HOR = 24;

typedef _Float16 f16;
typedef _Float16 f16x8 __attribute__((ext_vector_type(8)));
typedef float    f32x4 __attribute__((ext_vector_type(4)));

__device__ __forceinline__ float sigm(float x) { return 1.0f / (1.0f + expf(-x)); }

// ---------------------------------------------------------------------------
// Weight convert: fp32 [4H][H] gate-major rows (row = g*H + jh) -> fp16
// [2048][512] permuted rows n' = jh*4 + g. grid (512, 6).
__global__ __launch_bounds__(256)
void wconv_k(const float* __restrict__ s0, f16* __restrict__ d0,
             const float* __restrict__ s1, f16* __restrict__ d1,
             const float* __restrict__ s2, f16* __restrict__ d2,
             const float* __restrict__ s3, f16* __restrict__ d3,
             const float* __restrict__ s4, f16* __restrict__ d4,
             const float* __restrict__ s5, f16* __restrict__ d5)
{
    const float* src; f16* dst;
    switch (blockIdx.y) {
        case 0:  src = s0; dst = d0; break;
        case 1:  src = s1; dst = d1; break;
        case 2:  src = s2; dst = d2; break;
        case 3:  src = s3; dst = d3; break;
        case 4:  src = s4; dst = d4; break;
        default: src = s5; dst = d5; break;
    }
    int idx = (blockIdx.x * 256 + threadIdx.x) * 8;
    int np  = idx >> 9;
    int k   = idx & 511;
    int jh  = np >> 2, g = np & 3;
    const float* sp = src + (size_t)(g * H + jh) * H + k;
    f16 tmp[8];
    #pragma unroll
    for (int j = 0; j < 8; ++j) tmp[j] = (f16)sp[j];
    *(f16x8*)(dst + idx) = *(const f16x8*)tmp;
}

// ---------------------------------------------------------------------------
struct Chunk { f16x8 a0, a1, w0, w1; };

template<int BM>
__device__ __forceinline__ Chunk load_chunk(int kt,
    const f16* __restrict__ A0, const f16* __restrict__ A1,
    const f16* __restrict__ W0, const f16* __restrict__ W1,
    int b0, int n0, int asrow, int asch, int wsrow, int wsch)
{
    const f16* Ap = (kt < 8) ? A0 : A1;
    const f16* Wp = (kt < 8) ? W0 : W1;
    const int  ko = (kt < 8) ? kt * 64 : (kt - 8) * 64;
    Chunk c;
    if (BM == 64) {
        const f16* ap = Ap + (size_t)(b0 + asrow) * H + ko + asch * 16;
        c.a0 = *(const f16x8*)ap;
        c.a1 = *(const f16x8*)(ap + 8);
    } else {
        c.a0 = *(const f16x8*)(Ap + (size_t)(b0 + asrow) * H + ko + asch * 8);
        c.a1 = c.a0;
    }
    const f16* wp = Wp + (size_t)(n0 + wsrow) * H + ko + wsch * 16;
    c.w0 = *(const f16x8*)wp;
    c.w1 = *(const f16x8*)(wp + 8);
    return c;
}

// Fused LSTM cell tile, BM x 64 n' output, K = NKT*64.
// A rows k<512 from A0, else A1 (both [*][512] f16). W rows permuted n'=jh*4+g.
// LDS: double-buffered A/W chunks (BK=64, stride 72 halfs), one barrier/iter;
// next chunk's global loads issued AFTER the barrier so latency overlaps MFMA.
template<int BM, int NKT>
__device__ __forceinline__ void cell_body(int ridx, char* smem,
    const f16* __restrict__ A0, const f16* __restrict__ A1,
    const f16* __restrict__ W0, const f16* __restrict__ W1,
    const float* __restrict__ bih, const float* __restrict__ bhh,
    int xmode, const float* __restrict__ xptr, int xstride,
    const float* __restrict__ xw,
    float* __restrict__ cst, f16* __restrict__ hout)
{
    constexpr int FM   = BM / 32;      // 2 (BM=64) or 1 (BM=32)
    constexpr int MW   = 16 * FM;      // per-wave m rows
    constexpr int ABUF = 64 * 72;      // halfs per A buffer slot (max BM)
    constexpr int WBUF = 64 * 72;

    f16*   As = (f16*)smem;                          // [2][BM][72]
    f16*   Ws = (f16*)(smem + 2 * ABUF * 2);         // [2][64][72]
    float* zs = (float*)smem;                        // overlay after K-loop

    const int tid  = threadIdx.x;
    const int lane = tid & 63;
    const int wv   = tid >> 6;
    const int wm   = wv & 1;
    const int wn   = wv >> 1;
    const int r    = lane & 15;
    const int g4   = lane >> 4;
    const int bt   = ridx >> 5;
    const int nt   = ridx & 31;
    const int b0   = bt * BM;
    const int n0   = nt * 64;
    const int jh0  = nt * 16;

    const int wsrow = tid >> 2, wsch = tid & 3;                   // W: 16 halfs
    const int asrow = (BM == 64) ? (tid >> 2) : (tid >> 3);       // A rows
    const int asch  = (BM == 64) ? (tid & 3)  : (tid & 7);

    f32x4 acc[FM][2];
    #pragma unroll
    for (int i = 0; i < FM; ++i) { acc[i][0] = (f32x4)0.f; acc[i][1] = (f32x4)0.f; }

    Chunk cur = load_chunk<BM>(0, A0, A1, W0, W1, b0, n0, asrow, asch, wsrow, wsch);

    #pragma unroll
    for (int kt = 0; kt < NKT; ++kt) {
        const int p = kt & 1;
        f16* Ab = As + p * ABUF;
        f16* Wb = Ws + p * WBUF;
        if (BM == 64) {
            *(f16x8*)(Ab + asrow * 72 + asch * 16)     = cur.a0;
            *(f16x8*)(Ab + asrow * 72 + asch * 16 + 8) = cur.a1;
        } else {
            *(f16x8*)(Ab + asrow * 72 + asch * 8) = cur.a0;
        }
        *(f16x8*)(Wb + wsrow * 72 + wsch * 16)     = cur.w0;
        *(f16x8*)(Wb + wsrow * 72 + wsch * 16 + 8) = cur.w1;
        __syncthreads();

        Chunk nxt = cur;
        if (kt + 1 < NKT)
            nxt = load_chunk<BM>(kt + 1, A0, A1, W0, W1, b0, n0, asrow, asch, wsrow, wsch);

        #pragma unroll
        for (int sub = 0; sub < 2; ++sub) {
            f16x8 bf0 = *(const f16x8*)(Wb + (wn * 32 + r)      * 72 + sub * 32 + g4 * 8);
            f16x8 bf1 = *(const f16x8*)(Wb + (wn * 32 + 16 + r) * 72 + sub * 32 + g4 * 8);
            #pragma unroll
            for (int fm = 0; fm < FM; ++fm) {
                f16x8 af = *(const f16x8*)(Ab + (wm * MW + fm * 16 + r) * 72 + sub * 32 + g4 * 8);
                acc[fm][0] = __builtin_amdgcn_mfma_f32_16x16x32_f16(af, bf0, acc[fm][0], 0, 0, 0);
                acc[fm][1] = __builtin_amdgcn_mfma_f32_16x16x32_f16(af, bf1, acc[fm][1], 0, 0, 0);
            }
        }
        cur = nxt;
    }

    __syncthreads();   // last frag reads drained before zs overlay
    #pragma unroll
    for (int fm = 0; fm < FM; ++fm)
        #pragma unroll
        for (int fn = 0; fn < 2; ++fn)
            #pragma unroll
            for (int j = 0; j < 4; ++j)
                zs[(wm * MW + fm * 16 + g4 * 4 + j) * 68 +
                   (wn * 32 + fn * 16 + r)] = acc[fm][fn][j];
    __syncthreads();

    // epilogue: thread -> (BM/16 b-rows, 1 jh); gates = 4 consecutive n'.
    const int jl = tid & 15;
    const int bq = tid >> 4;
    const int jh = jh0 + jl;
    constexpr int RPT = BM / 16;

    float bsum[4];
    #pragma unroll
    for (int g = 0; g < 4; ++g) bsum[g] = bih[g * H + jh] + bhh[g * H + jh];

    #pragma unroll
    for (int bb = 0; bb < RPT; ++bb) {
        const int bl = bq * RPT + bb;
        const int b  = b0 + bl;
        float4 z = *(const float4*)(zs + bl * 68 + jl * 4);
        float zi = z.x + bsum[0];
        float zf = z.y + bsum[1];
        float zg = z.z + bsum[2];
        float zo = z.w + bsum[3];
        if (xmode == 1) {
            const float* xr = xptr + (size_t)b * xstride;
            #pragma unroll
            for (int k = 0; k < F; ++k) {
                float xv = xr[k];
                zi += xv * xw[(0 * H + jh) * F + k];
                zf += xv * xw[(1 * H + jh) * F + k];
                zg += xv * xw[(2 * H + jh) * F + k];
                zo += xv * xw[(3 * H + jh) * F + k];
            }
        } else if (xmode == 2) {
            float xv = xptr[b];
            zi += xv * xw[0 * H + jh];
            zf += xv * xw[1 * H + jh];
            zg += xv * xw[2 * H + jh];
            zo += xv * xw[3 * H + jh];
        }
        size_t idx = (size_t)b * H + jh;
        float cold = cst[idx];
        float cn = sigm(zf) * cold + sigm(zi) * tanhf(zg);
        cst[idx] = cn;
        hout[idx] = (f16)(sigm(zo) * tanhf(cn));
    }
}

// mode: 1 = layer0 only (grid 256), 2 = layer1 only (grid 512),
//       3 = both (grid 768: blocks [0,256) layer0, [256,768) layer1).
// layer0: BM=64, K=512 (A0=A1, W0=W1). layer1: BM=32, K=1024.
__global__ __launch_bounds__(256, 3)
void step_k(int mode,
    const f16* __restrict__ l0A, const f16* __restrict__ l0W,
    const float* __restrict__ l0bi, const float* __restrict__ l0bh,
    int xmode, const float* __restrict__ xptr, int xstride,
    const float* __restrict__ xw,
    float* __restrict__ l0c, f16* __restrict__ l0h,
    const f16* __restrict__ l1A0, const f16* __restrict__ l1A1,
    const f16* __restrict__ l1W0, const f16* __restrict__ l1W1,
    const float* __restrict__ l1bi, const float* __restrict__ l1bh,
    float* __restrict__ l1c, f16* __restrict__ l1h)
{
    __shared__ __align__(16) char smem[2 * 64 * 72 * 2 * 2];   // 36864 B
    const int bid = blockIdx.x;
    int role, ridx;
    if (mode == 3) { role = (bid >= 256); ridx = role ? bid - 256 : bid; }
    else           { role = (mode == 2);  ridx = bid; }
    if (!role)
        cell_body<64, 8>(ridx, smem, l0A, l0A, l0W, l0W, l0bi, l0bh,
                         xmode, xptr, xstride, xw, l0c, l0h);
    else
        cell_body<32, 16>(ridx, smem, l1A0, l1A1, l1W0, l1W1, l1bi, l1bh,
                          0, nullptr, 0, nullptr, l1c, l1h);
}

// ---------------------------------------------------------------------------
__global__ __launch_bounds__(256)
void pred16_k(const f16* __restrict__ h1, const float* __restrict__ outW,
              const float* __restrict__ outb, float* __restrict__ pred,
              float* __restrict__ dout, int tstep)
{
    int wv = threadIdx.x >> 6, lane = threadIdx.x & 63;
    int b = blockIdx.x * 4 + wv;
    const f16* hr = h1 + (size_t)b * H;
    float s = 0.f;
    #pragma unroll
    for (int k = 0; k < H; k += 64) s += (float)hr[k + lane] * outW[k + lane];
    #pragma unroll
    for (int off = 32; off > 0; off >>= 1) s += __shfl_down(s, off);
    if (lane == 0) {
        float p = s + outb[0];
        pred[b] = p;
        dout[(size_t)b * HOR + tstep] = p;
    }
}

__global__ void initpred_k(const float* __restrict__ x, float* __restrict__ pred)
{
    int b = blockIdx.x * 256 + threadIdx.x;
    if (b < B) pred[b] = x[(size_t)b * T * F + (size_t)(T - 1) * F];
}

// ---------------------------------------------------------------------------
extern "C" void kernel_launch(void* const* d_in, const int* in_sizes, int n_in,
                              void* d_out, int out_size, void* d_ws, size_t ws_size,
                              hipStream_t stream)
{
    const float* x     = (const float*)d_in[0];
    const float* eWih0 = (const float*)d_in[1];
    const float* eWhh0 = (const float*)d_in[2];
    const float* ebih0 = (const float*)d_in[3];
    const float* ebhh0 = (const float*)d_in[4];
    const float* eWih1 = (const float*)d_in[5];
    const float* eWhh1 = (const float*)d_in[6];
    const float* ebih1 = (const float*)d_in[7];
    const float* ebhh1 = (const float*)d_in[8];
    const float* dWih0 = (const float*)d_in[9];
    const float* dWhh0 = (const float*)d_in[10];
    const float* dbih0 = (const float*)d_in[11];
    const float* dbhh0 = (const float*)d_in[12];
    const float* dWih1 = (const float*)d_in[13];
    const float* dWhh1 = (const float*)d_in[14];
    const float* dbih1 = (const float*)d_in[15];
    const float* dbhh1 = (const float*)d_in[16];
    const float* outW  = (const float*)d_in[17];
    const float* outb  = (const float*)d_in[18];
    float* out = (float*)d_out;

    const size_t WSZ = (size_t)4 * H * H;
    const size_t BH  = (size_t)B * H;

    char* wsb = (char*)d_ws;
    size_t off = 0;
    f16* wh[6];
    for (int i = 0; i < 6; ++i) { wh[i] = (f16*)(wsb + off); off += WSZ * sizeof(f16); }
    f16* h0p[2]; f16* h1p[2];
    h0p[0] = (f16*)(wsb + off); off += BH * sizeof(f16);
    h0p[1] = (f16*)(wsb + off); off += BH * sizeof(f16);
    h1p[0] = (f16*)(wsb + off); off += BH * sizeof(f16);
    h1p[1] = (f16*)(wsb + off); off += BH * sizeof(f16);
    float* c0   = (float*)(wsb + off); off += BH * sizeof(float);
    float* c1   = (float*)(wsb + off); off += BH * sizeof(float);
    float* pred = (float*)(wsb + off); off += B * sizeof(float);

    wconv_k<<<dim3(512, 6), 256, 0, stream>>>(eWhh0, wh[0], eWih1, wh[1], eWhh1, wh[2],
                                              dWhh0, wh[3], dWih1, wh[4], dWhh1, wh[5]);

    hipMemsetAsync(h0p[1], 0, BH * sizeof(f16), stream);
    hipMemsetAsync(h1p[1], 0, BH * sizeof(f16), stream);
    hipMemsetAsync(c0, 0, BH * sizeof(float), stream);
    hipMemsetAsync(c1, 0, BH * sizeof(float), stream);

    dim3 blk(256);

    // Encoder, software-pipelined across kernel boundaries:
    // slot s runs layer0(t=s) and layer1(t=s-1) concurrently.
    // h0(t) lives in h0p[t&1]; h1(t) in h1p[t&1].
    for (int s = 0; s <= T; ++s) {
        int mode = (s == 0) ? 1 : (s == T) ? 2 : 3;
        int grid = (mode == 1) ? 256 : (mode == 2) ? 512 : 768;
        const f16* h0rd = h0p[(s + 1) & 1];   // h0(s-1)
        f16*       h0wr = h0p[s & 1];         // h0(s)
        const f16* h1rd = h1p[s & 1];         // h1(s-2)
        f16*       h1wr = h1p[(s + 1) & 1];   // h1(s-1)
        const float* xp = x + (size_t)((s < T) ? s : 0) * F;
        step_k<<<dim3(grid), blk, 0, stream>>>(mode,
            h0rd, wh[0], ebih0, ebhh0, 1, xp, T * F, eWih0, c0, h0wr,
            h0rd, h1rd, wh[1], wh[2], ebih1, ebhh1, c1, h1wr);
    }
    // encoder end: h0(255) in h0p[1], h1(255) in h1p[1]; c0,c1 in place.

    initpred_k<<<dim3(2), blk, 0, stream>>>(x, pred);

    for (int td = 0; td < HOR; ++td) {
        int rd = (td & 1) ^ 1, wr = td & 1;
        step_k<<<dim3(256), blk, 0, stream>>>(1,
            h0p[rd], wh[3], dbih0, dbhh0, 2, pred, 0, dWih0, c0, h0p[wr],
            nullptr, nullptr, nullptr, nullptr, nullptr, nullptr, nullptr, nullptr);
        step_k<<<dim3(512), blk, 0, stream>>>(2,
            nullptr, nullptr, nullptr, nullptr, 0, nullptr, 0, nullptr, nullptr, nullptr,
            h0p[wr], h1p[rd], wh[4], wh[5], dbih1, dbhh1, c1, h1p[wr]);
        pred16_k<<<dim3(128), blk, 0, stream>>>(h1p[wr], outW, outb, pred, out, td);
    }
}